// Round 1
// baseline (12660.126 us; speedup 1.0000x reference)
//
#include <hip/hip_runtime.h>
#include <math.h>

#define BB 2
#define TT_SEQ 1024
#define CDIM 1024
#define NH 16
#define NL 4
#define HD 64
#define NTOK (BB*TT_SEQ)   // 2048
#define VOCAB 50257

__device__ __forceinline__ float wave_sum(float v) {
#pragma unroll
    for (int o = 32; o; o >>= 1) v += __shfl_xor(v, o, 64);
    return v;
}

// -------- embedding: x[row,c] = tok_emb[idx[row],c] + pos_emb[row%T,c] ------
__global__ void embed_kernel(const int* __restrict__ idx,
                             const float* __restrict__ tok,
                             const float* __restrict__ pos,
                             float* __restrict__ x) {
    int row = blockIdx.x;          // 0..NTOK-1
    int t = row % TT_SEQ;
    int tokid = idx[row];
    const float4* te = (const float4*)(tok + (size_t)tokid * CDIM);
    const float4* pe = (const float4*)(pos + (size_t)t * CDIM);
    float4* xr = (float4*)(x + (size_t)row * CDIM);
    float4 a = te[threadIdx.x];
    float4 b = pe[threadIdx.x];
    a.x += b.x; a.y += b.y; a.z += b.z; a.w += b.w;
    xr[threadIdx.x] = a;
}

// -------- layernorm over C=1024, one block (256 thr) per row ---------------
__global__ void ln_kernel(const float* __restrict__ x,
                          const float* __restrict__ w,
                          const float* __restrict__ b,
                          float* __restrict__ out) {
    int row = blockIdx.x;
    int tid = threadIdx.x;
    int wid = tid >> 6, lane = tid & 63;
    __shared__ float red[8];
    float4 v = ((const float4*)(x + (size_t)row * CDIM))[tid];
    float s = v.x + v.y + v.z + v.w;
    s = wave_sum(s);
    if (lane == 0) red[wid] = s;
    __syncthreads();
    float mu = (red[0] + red[1] + red[2] + red[3]) * (1.0f / CDIM);
    float dx = v.x - mu, dy = v.y - mu, dz = v.z - mu, dw = v.w - mu;
    float s2 = dx*dx + dy*dy + dz*dz + dw*dw;
    s2 = wave_sum(s2);
    if (lane == 0) red[4 + wid] = s2;
    __syncthreads();
    float var = (red[4] + red[5] + red[6] + red[7]) * (1.0f / CDIM);
    float rs = rsqrtf(var + 1e-5f);
    float4 wv = ((const float4*)w)[tid];
    float4 bv = ((const float4*)b)[tid];
    float4 o;
    o.x = dx * rs * wv.x + bv.x;
    o.y = dy * rs * wv.y + bv.y;
    o.z = dz * rs * wv.z + bv.z;
    o.w = dw * rs * wv.w + bv.w;
    ((float4*)(out + (size_t)row * CDIM))[tid] = o;
}

// -------- NT GEMM: out[n,m] = sum_k A[n,k]*W[m,k]  (+bias)(gelu)(+resid) ---
// mode bit0: +bias[m]; bit1: exact gelu; bit2: +resid[n,m]
// TS = tile size (64 or 128), TT = per-thread tile (4 or 8); 256 threads.
template<int TS, int TT>
__global__ void gemm_nt(const float* __restrict__ A,
                        const float* __restrict__ W,
                        const float* __restrict__ bias,
                        const float* __restrict__ resid,
                        float* __restrict__ out,
                        int M, int K, int mode) {
    __shared__ float As[8][TS];
    __shared__ float Ws[8][TS];
    int tid = threadIdx.x;
    int tx = tid & 15, ty = tid >> 4;
    int n0 = blockIdx.x * TS;   // rows (N=2048, always multiple of TS)
    int m0 = blockIdx.y * TS;   // cols (W rows; may exceed M on last tile)

    float acc[TT][TT];
#pragma unroll
    for (int i = 0; i < TT; i++)
#pragma unroll
        for (int j = 0; j < TT; j++) acc[i][j] = 0.f;

    bool act = tid < TS * 2;    // TS*2 float4 loads per operand tile
    int ar = tid >> 1, kh = (tid & 1) * 4;

    for (int k0 = 0; k0 < K; k0 += 8) {
        float4 av = make_float4(0, 0, 0, 0), wv = make_float4(0, 0, 0, 0);
        if (act) {
            av = *(const float4*)(A + (size_t)(n0 + ar) * K + k0 + kh);
            int wrow = m0 + ar;
            if (wrow < M)
                wv = *(const float4*)(W + (size_t)wrow * K + k0 + kh);
        }
        __syncthreads();
        if (act) {
            As[kh + 0][ar] = av.x; As[kh + 1][ar] = av.y;
            As[kh + 2][ar] = av.z; As[kh + 3][ar] = av.w;
            Ws[kh + 0][ar] = wv.x; Ws[kh + 1][ar] = wv.y;
            Ws[kh + 2][ar] = wv.z; Ws[kh + 3][ar] = wv.w;
        }
        __syncthreads();
#pragma unroll
        for (int kk = 0; kk < 8; kk++) {
            float a[TT], w[TT];
#pragma unroll
            for (int i = 0; i < TT; i += 4)
                *(float4*)&a[i] = *(const float4*)&As[kk][ty * TT + i];
#pragma unroll
            for (int i = 0; i < TT; i += 4)
                *(float4*)&w[i] = *(const float4*)&Ws[kk][tx * TT + i];
#pragma unroll
            for (int i = 0; i < TT; i++)
#pragma unroll
                for (int j = 0; j < TT; j++)
                    acc[i][j] = fmaf(a[i], w[j], acc[i][j]);
        }
    }

#pragma unroll
    for (int i = 0; i < TT; i++) {
        int n = n0 + ty * TT + i;
#pragma unroll
        for (int j = 0; j < TT; j++) {
            int m = m0 + tx * TT + j;
            if (m < M) {
                float v = acc[i][j];
                if (mode & 1) v += bias[m];
                if (mode & 2) v = 0.5f * v * (1.0f + erff(v * 0.70710678118654752f));
                if (mode & 4) v += resid[(size_t)n * M + m];
                out[(size_t)n * M + m] = v;
            }
        }
    }
}

// -------- attention: wave-per-query-row online softmax ---------------------
// q,k,v laid out [B,T,C] with head h at cols h*64..h*64+63. lane = head dim.
__global__ void attn_kernel(const float* __restrict__ q,
                            const float* __restrict__ k,
                            const float* __restrict__ v,
                            float* __restrict__ y) {
    int wid = threadIdx.x >> 6;
    int lane = threadIdx.x & 63;
    int gw = blockIdx.x * 4 + wid;      // (b*NH + h)*T + qpos
    int qpos = gw % TT_SEQ;
    int bh = gw / TT_SEQ;
    int h = bh % NH;
    int b = bh / NH;
    const float scale = 0.125f;         // 1/sqrt(64)
    size_t base = ((size_t)b * TT_SEQ) * CDIM + h * HD + lane;
    float qd = q[base + (size_t)qpos * CDIM] * scale;
    const float* kp = k + base;
    const float* vp = v + base;
    float m = -INFINITY, l = 0.f, acc = 0.f;
    for (int kk = 0; kk <= qpos; kk++) {
        float kv = kp[(size_t)kk * CDIM];
        float s = wave_sum(qd * kv);
        float mn = fmaxf(m, s);
        float alpha = __expf(m - mn);   // exp(-inf)=0 on first iter
        float p = __expf(s - mn);
        l = l * alpha + p;
        acc = acc * alpha + p * vp[(size_t)kk * CDIM];
        m = mn;
    }
    y[base + (size_t)qpos * CDIM] = acc / l;
}

extern "C" void kernel_launch(void* const* d_in, const int* in_sizes, int n_in,
                              void* d_out, int out_size, void* d_ws, size_t ws_size,
                              hipStream_t stream) {
    (void)in_sizes; (void)n_in; (void)out_size; (void)ws_size;
    const int*   idx     = (const int*)d_in[0];
    const float* tok_emb = (const float*)d_in[1];
    const float* pos_emb = (const float*)d_in[2];
    const float* ln1_w   = (const float*)d_in[3];
    const float* ln1_b   = (const float*)d_in[4];
    const float* Wq      = (const float*)d_in[5];
    const float* bq      = (const float*)d_in[6];
    const float* Wk      = (const float*)d_in[7];
    const float* bk      = (const float*)d_in[8];
    const float* Wv      = (const float*)d_in[9];
    const float* bv      = (const float*)d_in[10];
    const float* Wo      = (const float*)d_in[11];
    const float* bo      = (const float*)d_in[12];
    const float* ln2_w   = (const float*)d_in[13];
    const float* ln2_b   = (const float*)d_in[14];
    const float* W1      = (const float*)d_in[15];
    const float* b1      = (const float*)d_in[16];
    const float* W2      = (const float*)d_in[17];
    const float* b2      = (const float*)d_in[18];
    const float* lnf_w   = (const float*)d_in[19];
    const float* lnf_b   = (const float*)d_in[20];
    const float* head_w  = (const float*)d_in[21];
    float* out = (float*)d_out;
    float* ws  = (float*)d_ws;

    const size_t S = (size_t)NTOK * CDIM;   // 2M floats = 8 MB
    float* x  = ws;
    float* h  = ws + S;
    float* qb = ws + 2 * S;
    float* kb = ws + 3 * S;
    float* vb = ws + 4 * S;
    float* yb = ws + 5 * S;
    float* h2 = ws + 6 * S;                 // 4*S floats

    embed_kernel<<<NTOK, 256, 0, stream>>>(idx, tok_emb, pos_emb, x);

    dim3 g64(NTOK / 64, CDIM / 64);               // 32 x 16
    dim3 g128m(NTOK / 128, 4 * CDIM / 128);       // 16 x 32
    for (int l = 0; l < NL; l++) {
        const size_t wcc = (size_t)l * CDIM * CDIM;
        ln_kernel<<<NTOK, 256, 0, stream>>>(x, ln1_w + l * CDIM, ln1_b + l * CDIM, h);
        gemm_nt<64, 4><<<g64, 256, 0, stream>>>(h, Wq + wcc, bq + l * CDIM, nullptr, qb, CDIM, CDIM, 1);
        gemm_nt<64, 4><<<g64, 256, 0, stream>>>(h, Wk + wcc, bk + l * CDIM, nullptr, kb, CDIM, CDIM, 1);
        gemm_nt<64, 4><<<g64, 256, 0, stream>>>(h, Wv + wcc, bv + l * CDIM, nullptr, vb, CDIM, CDIM, 1);
        attn_kernel<<<BB * NH * TT_SEQ / 4, 256, 0, stream>>>(qb, kb, vb, yb);
        gemm_nt<64, 4><<<g64, 256, 0, stream>>>(yb, Wo + wcc, bo + l * CDIM, x, x, CDIM, CDIM, 1 | 4);
        ln_kernel<<<NTOK, 256, 0, stream>>>(x, ln2_w + l * CDIM, ln2_b + l * CDIM, h);
        gemm_nt<128, 8><<<g128m, 256, 0, stream>>>(h, W1 + (size_t)l * 4 * CDIM * CDIM,
                                                   b1 + l * 4 * CDIM, nullptr, h2, 4 * CDIM, CDIM, 1 | 2);
        gemm_nt<64, 4><<<g64, 256, 0, stream>>>(h2, W2 + (size_t)l * CDIM * 4 * CDIM,
                                                b2 + l * CDIM, x, x, CDIM, 4 * CDIM, 1 | 4);
    }
    ln_kernel<<<NTOK, 256, 0, stream>>>(x, lnf_w, lnf_b, h);
    dim3 gh(NTOK / 128, (VOCAB + 127) / 128);     // 16 x 393
    gemm_nt<128, 8><<<gh, 256, 0, stream>>>(h, head_w, nullptr, nullptr, out, VOCAB, CDIM, 0);
}